// Round 8
// baseline (1442.696 us; speedup 1.0000x reference)
//
#include <hip/hip_runtime.h>
#include <hip/hip_bf16.h>
#include <math.h>

// ---- problem constants ----
#define HIDN 7168
#define NHEAD 128
#define QLRANK 1536
#define KVLRANK 512
#define QKD 128
#define VHD 128
#define RHD 64
#define SEQ 1024
#define RMS_EPS 1.1920929e-07f

typedef unsigned short u16;
typedef __attribute__((ext_vector_type(8))) short bf16x8;
typedef __attribute__((ext_vector_type(4))) float f32x4;
typedef __attribute__((ext_vector_type(8))) unsigned short u16x8;

__device__ __forceinline__ u16 f2bf(float f) {
    unsigned int u = __float_as_uint(f);
    unsigned int r = (u + 0x7FFFu + ((u >> 16) & 1u)) >> 16;
    return (u16)r;
}
__device__ __forceinline__ float bf2f(u16 v) {
    return __uint_as_float(((unsigned int)v) << 16);
}

// async global->LDS, 16B per lane. LDS dest is wave-uniform base + lane*16.
__device__ __forceinline__ void gld_lds16(const u16* g, u16* l) {
    __builtin_amdgcn_global_load_lds(
        (const __attribute__((address_space(1))) unsigned int*)g,
        (__attribute__((address_space(3))) unsigned int*)l,
        16, 0, 0);
}

// ---------------- fp32 -> bf16 conversion (x8 vectorized) ----------------
__global__ __launch_bounds__(256) void f32_to_bf16(const float* __restrict__ in,
                                                   u16* __restrict__ out, long n) {
    long i = ((long)blockIdx.x * blockDim.x + threadIdx.x) * 8;
    long stride = (long)gridDim.x * blockDim.x * 8;
    for (; i < n; i += stride) {
        float4 a = *(const float4*)(in + i);
        float4 b = *(const float4*)(in + i + 4);
        u16x8 o;
        o[0] = f2bf(a.x); o[1] = f2bf(a.y); o[2] = f2bf(a.z); o[3] = f2bf(a.w);
        o[4] = f2bf(b.x); o[5] = f2bf(b.y); o[6] = f2bf(b.z); o[7] = f2bf(b.w);
        *(u16x8*)(out + i) = o;
    }
}

// ---------------- generic GEMM: C[m][n] = sum_k A[m][k]*B[n][k] ----------------
// T4 counted-vmcnt pipeline: 128x128 tile, BK=64, 4 waves, 4-buffer LDS ring
// (128 KiB -> 1 block/CU; pipeline depth replaces TLP, m201 precedent).
// Schedule per K-step: vmcnt(16) [tile t landed, t+1/t+2 stay in flight] ->
// s_barrier -> stage(t+3) -> compute(t). ONE barrier per step; never drains
// vmcnt to 0 in steady state (catalog T4, m218's +38-73% lever).
// Race-safety: top-barrier ensures all waves finished compute(t) before any
// wave issues stage(t+4) which overwrites buf t&3; in-flight stages during
// compute(t) target bufs (t+1..t+3)&3 != t&3.
// Staging map: r3-proven coalesced row-grouped source + XOR chunk swizzle
// (8 lanes cover one 128B row; LDS dest linear; read side shares the XOR).
// Split-K via blockIdx.z: fp32 partials at Cv + z*M*N (OUT_BF16=0 only).
template <int OUT_BF16>
__global__ __launch_bounds__(256) void gemm_bt(const u16* __restrict__ A,
                                               const u16* __restrict__ B,
                                               void* __restrict__ Cv,
                                               int M, int N, int Kslice, long ldk) {
    __shared__ u16 As[4 * 128 * 64];   // 64 KiB
    __shared__ u16 Bs[4 * 128 * 64];   // 64 KiB
    const int tid = threadIdx.x;
    const int lane = tid & 63;
    const int w = tid >> 6;
    const int wr = w >> 1, wc = w & 1;
    const int l15 = lane & 15, lg = lane >> 4;
    const int n0 = blockIdx.x * 128;
    const int m0 = blockIdx.y * 128;
    const long kbase = (long)blockIdx.z * Kslice;

    // staging: 4 issues per wave per matrix; each issue = 8 rows x 64 cols.
    // lane covers row (base + lane>>3), 16B chunk p=lane&7; global chunk p^(r&7).
    const u16* asrc[4];
    const u16* bsrc[4];
    int aoff[4];
#pragma unroll
    for (int i = 0; i < 4; ++i) {
        int r = (w * 4 + i) * 8 + (lane >> 3);
        int gc = (lane & 7) ^ (r & 7);
        asrc[i] = A + (long)(m0 + r) * ldk + kbase + gc * 8;
        int br = n0 + r; if (br >= N) br = N - 1;
        bsrc[i] = B + (long)br * ldk + kbase + gc * 8;
        aoff[i] = (w * 4 + i) * 512;
    }

    f32x4 acc[4][4];
    const f32x4 z = {0.f, 0.f, 0.f, 0.f};
#pragma unroll
    for (int i = 0; i < 4; ++i)
#pragma unroll
        for (int j = 0; j < 4; ++j) acc[i][j] = z;

    auto stage = [&](int t) {
        const int bb = (t & 3) * 8192;
        const long ko = (long)t * 64;
#pragma unroll
        for (int i = 0; i < 4; ++i) {
            gld_lds16(asrc[i] + ko, As + bb + aoff[i]);
            gld_lds16(bsrc[i] + ko, Bs + bb + aoff[i]);
        }
    };

    const int nsteps = Kslice >> 6;
    stage(0);
    if (1 < nsteps) stage(1);
    if (2 < nsteps) stage(2);

    for (int t = 0; t < nsteps; ++t) {
        if (t + 2 < nsteps)      asm volatile("s_waitcnt vmcnt(16)" ::: "memory");
        else if (t + 1 < nsteps) asm volatile("s_waitcnt vmcnt(8)" ::: "memory");
        else                     asm volatile("s_waitcnt vmcnt(0)" ::: "memory");
        __builtin_amdgcn_s_barrier();
        __builtin_amdgcn_sched_barrier(0);
        if (t + 3 < nsteps) stage(t + 3);
        const u16* Ab = As + (t & 3) * 8192;
        const u16* Bb = Bs + (t & 3) * 8192;
#pragma unroll
        for (int kk = 0; kk < 2; ++kk) {
            bf16x8 a[4], b[4];
#pragma unroll
            for (int i = 0; i < 4; ++i) {
                int row = wr * 64 + i * 16 + l15;
                a[i] = *(const bf16x8*)&Ab[row * 64 + ((kk * 4 + lg) ^ (row & 7)) * 8];
            }
#pragma unroll
            for (int j = 0; j < 4; ++j) {
                int row = wc * 64 + j * 16 + l15;
                b[j] = *(const bf16x8*)&Bb[row * 64 + ((kk * 4 + lg) ^ (row & 7)) * 8];
            }
#pragma unroll
            for (int i = 0; i < 4; ++i)
#pragma unroll
                for (int j = 0; j < 4; ++j)
                    acc[i][j] = __builtin_amdgcn_mfma_f32_16x16x32_bf16(a[i], b[j], acc[i][j], 0, 0, 0);
        }
    }

#pragma unroll
    for (int i = 0; i < 4; ++i)
#pragma unroll
        for (int j = 0; j < 4; ++j)
#pragma unroll
            for (int r = 0; r < 4; ++r) {
                int m = m0 + wr * 64 + i * 16 + lg * 4 + r;
                int n = n0 + wc * 64 + j * 16 + l15;
                if (n < N) {
                    if (OUT_BF16)
                        ((u16*)Cv)[(long)m * N + n] = f2bf(acc[i][j][r]);
                    else
                        ((float*)Cv)[(long)blockIdx.z * M * N + (long)m * N + n] = acc[i][j][r];
                }
            }
}

// ---------------- sum split-K partials (fp32), x4 vectorized ----------------
__global__ __launch_bounds__(256) void reduce_parts(const float* __restrict__ parts,
                                                    float* __restrict__ out,
                                                    int nparts, long mn) {
    long i = ((long)blockIdx.x * 256 + threadIdx.x) * 4;
    long stride = (long)gridDim.x * 256 * 4;
    for (; i < mn; i += stride) {
        float4 s = *(const float4*)(parts + i);
        for (int p = 1; p < nparts; ++p) {
            float4 v = *(const float4*)(parts + (long)p * mn + i);
            s.x += v.x; s.y += v.y; s.z += v.z; s.w += v.w;
        }
        *(float4*)(out + i) = s;
    }
}

// ---------------- RMSNorm (row-wise): y = x * rsqrt(mean(x^2)+eps) * w ----------------
__global__ __launch_bounds__(256) void rmsnorm_kernel(const float* __restrict__ x,
                                                      const float* __restrict__ w,
                                                      u16* __restrict__ y,
                                                      int stride, int norm_len) {
    const int row = blockIdx.x;
    const float* xr = x + (long)row * stride;
    float ss = 0.f;
    for (int i = threadIdx.x; i < norm_len; i += 256) {
        float v = xr[i];
        ss += v * v;
    }
#pragma unroll
    for (int off = 32; off > 0; off >>= 1) ss += __shfl_down(ss, off);
    __shared__ float partial[4];
    if ((threadIdx.x & 63) == 0) partial[threadIdx.x >> 6] = ss;
    __syncthreads();
    float tot = partial[0] + partial[1] + partial[2] + partial[3];
    float rs = 1.0f / sqrtf(tot / (float)norm_len + RMS_EPS);
    u16* yr = y + (long)row * norm_len;
    for (int i = threadIdx.x; i < norm_len; i += 256) yr[i] = f2bf(xr[i] * rs * w[i]);
}

// ---------------- RoPE tables (fp32): cos/sin[s][i], i<32 ----------------
__global__ void rope_tables(float* __restrict__ cos_t, float* __restrict__ sin_t) {
    int s = blockIdx.x;
    int i = threadIdx.x;  // 32 threads
    float invf = powf(10000.0f, -((float)(2 * i) / 64.0f));
    float ang = (float)s * invf;
    cos_t[s * 32 + i] = cosf(ang);
    sin_t[s * 32 + i] = sinf(ang);
}

// ---------------- RoPE on q_r, in-place on q_cr (bf16) ----------------
__global__ void rope_q(u16* __restrict__ q_cr, const float* __restrict__ cos_t,
                       const float* __restrict__ sin_t) {
    int s = blockIdx.x;
    int h = blockIdx.y * 2 + (threadIdx.x >> 5);
    int i = threadIdx.x & 31;
    u16* base = q_cr + (s * (NHEAD * 192) + h * 192 + QKD);
    float x1 = bf2f(base[i]);
    float x2 = bf2f(base[i + 32]);
    float c = cos_t[s * 32 + i], sn = sin_t[s * 32 + i];
    base[i]      = f2bf(x1 * c - x2 * sn);
    base[i + 32] = f2bf(x2 * c + x1 * sn);
}

// ---------------- RoPE on k_r (from fp32 ckv_kr cols 512..576) -> bf16 kr ----------------
__global__ void rope_k(const float* __restrict__ ckv_kr, const float* __restrict__ cos_t,
                       const float* __restrict__ sin_t, u16* __restrict__ kr) {
    int s = blockIdx.x;
    int i = threadIdx.x;  // 64 threads; first 32 active
    if (i < 32) {
        const float* base = ckv_kr + (s * 576 + 512);
        float x1 = base[i], x2 = base[i + 32];
        float c = cos_t[s * 32 + i], sn = sin_t[s * 32 + i];
        kr[s * 64 + i]      = f2bf(x1 * c - x2 * sn);
        kr[s * 64 + i + 32] = f2bf(x2 * c + x1 * sn);
    }
}

// ---------------- build vT[h][dv][s] from kv[s][h*256+128+dv] ----------------
__global__ __launch_bounds__(256) void build_vt(const u16* __restrict__ kv,
                                                u16* __restrict__ vT) {
    __shared__ u16 vtile[64][136];  // 272B row stride (16B aligned)
    const int h = blockIdx.x, sb = blockIdx.y, s0 = sb * 64;
    const int tid = threadIdx.x;
#pragma unroll
    for (int it = 0; it < 4; ++it) {
        int c = it * 256 + tid;
        int row = c >> 4;
        int off8 = (c & 15) * 8;
        *(u16x8*)&vtile[row][off8] =
            *(const u16x8*)&kv[(s0 + row) * 32768 + h * 256 + 128 + off8];
    }
    __syncthreads();
    const int sl = tid & 63;
    const int dvb = tid >> 6;  // 0..3
#pragma unroll
    for (int it = 0; it < 32; ++it) {
        int dv = dvb + it * 4;
        vT[(h * 128 + dv) * 1024 + s0 + sl] = vtile[sl][dv];
    }
}

// ---------------- flash attention: 1 block = 128 queries x 1 head, 8 waves ----------------
// T14 async-STAGE: tile t+1 global loads issued right after tile t's staging
// barrier (latency hides under QK^T+softmax+PV); regs written to LDS after the
// next loop-top barrier. p_lds is wave-private -> no barrier after P-write
// (in-wave ds_write->ds_read ordered by lgkmcnt). 2 barriers per K/V tile.
__global__ __launch_bounds__(512) void mla_attn(const u16* __restrict__ q_cr,
                                                const u16* __restrict__ kv,
                                                const u16* __restrict__ kr,
                                                const u16* __restrict__ vT,
                                                u16* __restrict__ o_g) {
    __shared__ u16 ks[64][200];        // 64 keys x 192 dims (+pad)
    __shared__ u16 vts[128][72];       // 128 dv x 64 k (+pad)
    __shared__ u16 p_lds[8][16][72];   // per wave: 16 q x 64 k (+pad)
    const int qb = blockIdx.x, h = blockIdx.y;
    const int s0q = qb * 128;
    const int tid = threadIdx.x, lane = tid & 63, w = tid >> 6;
    const int l15 = lane & 15, lg = lane >> 4;
    const float scale = 0.07216878364870323f;  // 1/sqrt(192)

    // Q in registers, A-fragment layout (row = l15, k contiguous per lg group)
    bf16x8 qreg[6];
    {
        const int qrow = s0q + w * 16 + l15;
#pragma unroll
        for (int kk = 0; kk < 6; ++kk)
            qreg[kk] = *(const bf16x8*)&q_cr[qrow * (NHEAD * 192) + h * 192 + kk * 32 + lg * 8];
    }

    // staging-index precompute (512 threads cover: K 2x, kr 1x, V 2x u16x8 each)
    const int krow0 = tid >> 4,           koff0 = (tid & 15) * 8;
    const int krow1 = (512 + tid) >> 4,   koff1 = ((512 + tid) & 15) * 8;
    const int rrow  = tid >> 3,           roff  = (tid & 7) * 8;
    const int vdv0  = tid >> 3,           voff0 = (tid & 7) * 8;
    const int vdv1  = (512 + tid) >> 3,   voff1 = ((512 + tid) & 7) * 8;
    const u16* kvp = kv + h * 256;
    const u16* vtp = vT + (long)(h * 128) * 1024;

    u16x8 kreg0, kreg1, krreg, vreg0, vreg1;
    auto load_tile = [&](int s0k) {
        kreg0 = *(const u16x8*)&kvp[(long)(s0k + krow0) * 32768 + koff0];
        kreg1 = *(const u16x8*)&kvp[(long)(s0k + krow1) * 32768 + koff1];
        krreg = *(const u16x8*)&kr[(s0k + rrow) * 64 + roff];
        vreg0 = *(const u16x8*)&vtp[(long)vdv0 * 1024 + s0k + voff0];
        vreg1 = *(const u16x8*)&vtp[(long)vdv1 * 1024 + s0k + voff1];
    };

    f32x4 o_acc[8];
    const f32x4 z = {0.f, 0.f, 0.f, 0.f};
#pragma unroll
    for (int d = 0; d < 8; ++d) o_acc[d] = z;
    float m_r[4], l_r[4];
#pragma unroll
    for (int r = 0; r < 4; ++r) { m_r[r] = -1e30f; l_r[r] = 0.f; }

    load_tile(0);

    for (int kt = 0; kt < 16; ++kt) {
        __syncthreads();   // prev tile's readers done
        *(u16x8*)&ks[krow0][koff0]      = kreg0;
        *(u16x8*)&ks[krow1][koff1]      = kreg1;
        *(u16x8*)&ks[rrow][128 + roff]  = krreg;
        *(u16x8*)&vts[vdv0][voff0]      = vreg0;
        *(u16x8*)&vts[vdv1][voff1]      = vreg1;
        __syncthreads();   // tile staged
        if (kt + 1 < 16) load_tile((kt + 1) * 64);   // async: hides under compute

        // QK^T : S-frags (16 q x 64 keys per wave)
        f32x4 sf[4];
#pragma unroll
        for (int j = 0; j < 4; ++j) sf[j] = z;
#pragma unroll
        for (int kk = 0; kk < 6; ++kk) {
            bf16x8 a = qreg[kk];
#pragma unroll
            for (int j = 0; j < 4; ++j) {
                bf16x8 b = *(const bf16x8*)&ks[j * 16 + l15][kk * 32 + lg * 8];
                sf[j] = __builtin_amdgcn_mfma_f32_16x16x32_bf16(a, b, sf[j], 0, 0, 0);
            }
        }

        // online softmax (rows live in C-layout: row=(lg)*4+r, col=j*16+l15)
        float p[4][4];
        float alpha[4];
#pragma unroll
        for (int r = 0; r < 4; ++r) {
            float mx = fmaxf(fmaxf(sf[0][r], sf[1][r]), fmaxf(sf[2][r], sf[3][r]));
#pragma unroll
            for (int off = 1; off < 16; off <<= 1) mx = fmaxf(mx, __shfl_xor(mx, off));
            mx *= scale;
            float mnew = fmaxf(m_r[r], mx);
            alpha[r] = __expf(m_r[r] - mnew);
            float rs = 0.f;
#pragma unroll
            for (int j = 0; j < 4; ++j) {
                float pv = __expf(sf[j][r] * scale - mnew);
                p[j][r] = pv;
                rs += pv;
            }
#pragma unroll
            for (int off = 1; off < 16; off <<= 1) rs += __shfl_xor(rs, off);
            l_r[r] = l_r[r] * alpha[r] + rs;
            m_r[r] = mnew;
        }
#pragma unroll
        for (int d = 0; d < 8; ++d)
#pragma unroll
            for (int r = 0; r < 4; ++r) o_acc[d][r] *= alpha[r];

        // P -> LDS (wave-private; no block barrier needed)
#pragma unroll
        for (int j = 0; j < 4; ++j)
#pragma unroll
            for (int r = 0; r < 4; ++r)
                p_lds[w][lg * 4 + r][j * 16 + l15] = f2bf(p[j][r]);

        // PV: O += P @ V
#pragma unroll
        for (int kk2 = 0; kk2 < 2; ++kk2) {
            bf16x8 a = *(const bf16x8*)&p_lds[w][l15][kk2 * 32 + lg * 8];
#pragma unroll
            for (int d = 0; d < 8; ++d) {
                bf16x8 b = *(const bf16x8*)&vts[d * 16 + l15][kk2 * 32 + lg * 8];
                o_acc[d] = __builtin_amdgcn_mfma_f32_16x16x32_bf16(a, b, o_acc[d], 0, 0, 0);
            }
        }
    }

    // epilogue: divide by l, store bf16 o[s][h*128+dv]
#pragma unroll
    for (int d = 0; d < 8; ++d)
#pragma unroll
        for (int r = 0; r < 4; ++r) {
            int srow = s0q + w * 16 + lg * 4 + r;
            float v = o_acc[d][r] / l_r[r];
            o_g[srow * 16384 + h * 128 + d * 16 + l15] = f2bf(v);
        }
}

// ---------------- host launcher ----------------
extern "C" void kernel_launch(void* const* d_in, const int* in_sizes, int n_in,
                              void* d_out, int out_size, void* d_ws, size_t ws_size,
                              hipStream_t stream) {
    const float* hs        = (const float*)d_in[0];
    const float* w_q_down  = (const float*)d_in[1];
    const float* q_norm_w  = (const float*)d_in[2];
    const float* w_q_up    = (const float*)d_in[3];
    const float* w_kv_down = (const float*)d_in[4];
    const float* kv_norm_w = (const float*)d_in[5];
    const float* w_kv_up   = (const float*)d_in[6];
    const float* w_out     = (const float*)d_in[7];
    float* out = (float*)d_out;
    char* ws = (char*)d_ws;

    // ---- workspace layout (contiguous front region is reused for w_out bf16) ----
    const size_t SZ_HS   = (size_t)SEQ * HIDN * 2;            // 14,680,064
    const size_t SZ_KV   = (size_t)SEQ * 32768 * 2;           // 67,108,864
    const size_t SZ_QCR  = (size_t)SEQ * (NHEAD * 192) * 2;   // 50,331,648
    const size_t SZ_VT   = (size_t)NHEAD * 128 * 1024 * 2;    // 33,554,432
    const size_t SZ_WB   = (size_t)24576 * 1536 * 2;          // 75,497,472 (max of small weights)
    const size_t SZ_CQ   = (size_t)SEQ * QLRANK * 4;
    const size_t SZ_CQN  = (size_t)SEQ * QLRANK * 2;
    const size_t SZ_CKV  = (size_t)SEQ * 576 * 4;
    const size_t SZ_CKVN = (size_t)SEQ * KVLRANK * 2;
    const size_t SZ_KR   = (size_t)SEQ * 64 * 2;
    const size_t SZ_OG   = (size_t)SEQ * 16384 * 2;
    const size_t SZ_TAB  = (size_t)SEQ * 32 * 4;

    size_t off = 0;
    u16* hs_bf  = (u16*)(ws + off); off += SZ_HS;
    u16* kvb    = (u16*)(ws + off); off += SZ_KV;
    u16* q_cr   = (u16*)(ws + off); off += SZ_QCR;
    u16* vT     = (u16*)(ws + off); off += SZ_VT;
    u16* W_BUF  = (u16*)(ws + off); off += SZ_WB;
    // split-K partials for c_q/kv_down alias upper W_BUF region (+32MB; weight
    // there is <32MB while these gemms run).
    float* parts = (float*)((char*)W_BUF + 33554432);
    // w_out bf16 (234,881,024 B) aliases [ws .. 235MB), all dead by then
    u16* wout_bf = (u16*)ws;
    float* c_q    = (float*)(ws + off); off += SZ_CQ;
    u16* cq_n     = (u16*)(ws + off); off += SZ_CQN;
    float* ckv_kr = (float*)(ws + off); off += SZ_CKV;
    u16* ckv_n    = (u16*)(ws + off); off += SZ_CKVN;
    u16* kr       = (u16*)(ws + off); off += SZ_KR;
    u16* o_g      = (u16*)(ws + off); off += SZ_OG;
    float* cos_t  = (float*)(ws + off); off += SZ_TAB;
    float* sin_t  = (float*)(ws + off); off += SZ_TAB;
    (void)in_sizes; (void)n_in; (void)out_size; (void)ws_size;

    rope_tables<<<dim3(SEQ), dim3(32), 0, stream>>>(cos_t, sin_t);
    f32_to_bf16<<<2048, 256, 0, stream>>>(hs, hs_bf, (long)SEQ * HIDN);

    // c_q = hs @ w_q_down^T   (split-K x4: 7168 = 4 x 1792)
    f32_to_bf16<<<2048, 256, 0, stream>>>(w_q_down, W_BUF, (long)QLRANK * HIDN);
    gemm_bt<0><<<dim3(QLRANK / 128, SEQ / 128, 4), 256, 0, stream>>>(hs_bf, W_BUF, parts, SEQ, QLRANK, HIDN / 4, HIDN);
    reduce_parts<<<1024, 256, 0, stream>>>(parts, c_q, 4, (long)SEQ * QLRANK);
    rmsnorm_kernel<<<SEQ, 256, 0, stream>>>(c_q, q_norm_w, cq_n, QLRANK, QLRANK);

    // q_cr = rmsnorm(c_q) @ w_q_up^T
    f32_to_bf16<<<2048, 256, 0, stream>>>(w_q_up, W_BUF, (long)24576 * QLRANK);
    gemm_bt<1><<<dim3(24576 / 128, SEQ / 128), 256, 0, stream>>>(cq_n, W_BUF, q_cr, SEQ, 24576, QLRANK, QLRANK);

    // ckv_kr = hs @ w_kv_down^T   (split-K x8: 7168 = 8 x 896; N=576 ragged)
    f32_to_bf16<<<2048, 256, 0, stream>>>(w_kv_down, W_BUF, (long)576 * HIDN);
    gemm_bt<0><<<dim3(5, SEQ / 128, 8), 256, 0, stream>>>(hs_bf, W_BUF, parts, SEQ, 576, HIDN / 8, HIDN);
    reduce_parts<<<1024, 256, 0, stream>>>(parts, ckv_kr, 8, (long)SEQ * 576);
    rmsnorm_kernel<<<SEQ, 256, 0, stream>>>(ckv_kr, kv_norm_w, ckv_n, 576, KVLRANK);
    rope_k<<<SEQ, 64, 0, stream>>>(ckv_kr, cos_t, sin_t, kr);

    // kv = rmsnorm(c_kv) @ w_kv_up^T
    f32_to_bf16<<<2048, 256, 0, stream>>>(w_kv_up, W_BUF, (long)32768 * KVLRANK);
    gemm_bt<1><<<dim3(32768 / 128, SEQ / 128), 256, 0, stream>>>(ckv_n, W_BUF, kvb, SEQ, 32768, KVLRANK, KVLRANK);

    rope_q<<<dim3(SEQ, NHEAD / 2), 64, 0, stream>>>(q_cr, cos_t, sin_t);
    build_vt<<<dim3(NHEAD, SEQ / 64), 256, 0, stream>>>(kvb, vT);

    mla_attn<<<dim3(SEQ / 128, NHEAD), 512, 0, stream>>>(q_cr, kvb, kr, vT, o_g);

    // out = o @ w_out^T   (w_out bf16 aliases the now-dead front region)
    // No split-K: partial traffic (r7: +230MB HBM) costs more than it buys.
    f32_to_bf16<<<4096, 256, 0, stream>>>(w_out, wout_bf, (long)HIDN * 16384);
    gemm_bt<0><<<dim3(HIDN / 128, SEQ / 128), 256, 0, stream>>>(o_g, wout_bf, out, SEQ, HIDN, 16384, 16384);
}

// Round 9
// 1017.224 us; speedup vs baseline: 1.4183x; 1.4183x over previous
//
#include <hip/hip_runtime.h>
#include <hip/hip_bf16.h>
#include <math.h>

// ---- problem constants ----
#define HIDN 7168
#define NHEAD 128
#define QLRANK 1536
#define KVLRANK 512
#define QKD 128
#define VHD 128
#define RHD 64
#define SEQ 1024
#define RMS_EPS 1.1920929e-07f

typedef unsigned short u16;
typedef __attribute__((ext_vector_type(8))) short bf16x8;
typedef __attribute__((ext_vector_type(4))) float f32x4;
typedef __attribute__((ext_vector_type(8))) unsigned short u16x8;

__device__ __forceinline__ u16 f2bf(float f) {
    unsigned int u = __float_as_uint(f);
    unsigned int r = (u + 0x7FFFu + ((u >> 16) & 1u)) >> 16;
    return (u16)r;
}
__device__ __forceinline__ float bf2f(u16 v) {
    return __uint_as_float(((unsigned int)v) << 16);
}

// async global->LDS, 16B per lane. LDS dest is wave-uniform base + lane*16.
__device__ __forceinline__ void gld_lds16(const u16* g, u16* l) {
    __builtin_amdgcn_global_load_lds(
        (const __attribute__((address_space(1))) unsigned int*)g,
        (__attribute__((address_space(3))) unsigned int*)l,
        16, 0, 0);
}

// ---------------- fp32 -> bf16 conversion (x8 vectorized) ----------------
__global__ __launch_bounds__(256) void f32_to_bf16(const float* __restrict__ in,
                                                   u16* __restrict__ out, long n) {
    long i = ((long)blockIdx.x * blockDim.x + threadIdx.x) * 8;
    long stride = (long)gridDim.x * blockDim.x * 8;
    for (; i < n; i += stride) {
        float4 a = *(const float4*)(in + i);
        float4 b = *(const float4*)(in + i + 4);
        u16x8 o;
        o[0] = f2bf(a.x); o[1] = f2bf(a.y); o[2] = f2bf(a.z); o[3] = f2bf(a.w);
        o[4] = f2bf(b.x); o[5] = f2bf(b.y); o[6] = f2bf(b.z); o[7] = f2bf(b.w);
        *(u16x8*)(out + i) = o;
    }
}

// ---------------- generic GEMM: C[m][n] = sum_k A[m][k]*B[n][k] ----------------
// r3-proven 2-phase dbuf structure, widened to 8 WAVES (512 threads) on the
// same 128x128 tile: per-wave output 64x32 (acc 4x2). LDS stays 64 KiB ->
// 2 blocks/CU x 8 waves = 16 waves/CU = 4 waves/SIMD (2x r3's TLP; the
// occupancy lever r8 proved decisive: 1 wave/SIMD exposes all latency).
// Staging: global_load_lds(16), coalesced row-grouped source map + XOR chunk
// swizzle (0 bank conflicts, FETCH ~= ideal). One vmcnt(0)+s_barrier per
// K-step; the drain is masked by cross-wave TLP (m114).
// T1 bijective XCD swizzle on (x,y) per z-slice (all grids %8==0).
// Split-K via blockIdx.z: fp32 partials at Cv + z*M*N (OUT_BF16=0 only).
template <int OUT_BF16>
__global__ __launch_bounds__(512) void gemm_bt(const u16* __restrict__ A,
                                               const u16* __restrict__ B,
                                               void* __restrict__ Cv,
                                               int M, int N, int Kslice, long ldk) {
    __shared__ u16 As[2 * 128 * 64];   // 2 x 16 KiB
    __shared__ u16 Bs[2 * 128 * 64];
    const int tid = threadIdx.x;
    const int lane = tid & 63;
    const int w = tid >> 6;            // 0..7
    const int wr = w >> 2, wc = w & 3; // wave grid 2M x 4N
    const int l15 = lane & 15, lg = lane >> 4;

    // T1: bijective XCD-chunked remap of (x,y) within this z-slice
    const int nwg = gridDim.x * gridDim.y;           // divisible by 8 for all launches
    const int lin = blockIdx.y * gridDim.x + blockIdx.x;
    const int wg  = (lin & 7) * (nwg >> 3) + (lin >> 3);
    const int n0 = (wg % gridDim.x) * 128;
    const int m0 = (wg / gridDim.x) * 128;
    const long kbase = (long)blockIdx.z * Kslice;

    // staging: 2 issues per wave per matrix; each issue = 8 rows x 64 cols.
    // lane covers row (base + lane>>3), 16B chunk p=lane&7; global chunk p^(r&7).
    const u16* asrc[2];
    const u16* bsrc[2];
    int aoff[2];
#pragma unroll
    for (int i = 0; i < 2; ++i) {
        int r = (w * 2 + i) * 8 + (lane >> 3);
        int gc = (lane & 7) ^ (r & 7);
        asrc[i] = A + (long)(m0 + r) * ldk + kbase + gc * 8;
        int br = n0 + r; if (br >= N) br = N - 1;
        bsrc[i] = B + (long)br * ldk + kbase + gc * 8;
        aoff[i] = (w * 2 + i) * 512;
    }

    f32x4 acc[4][2];
    const f32x4 z = {0.f, 0.f, 0.f, 0.f};
#pragma unroll
    for (int i = 0; i < 4; ++i)
#pragma unroll
        for (int j = 0; j < 2; ++j) acc[i][j] = z;

    auto stage = [&](int bufi, int kofs) {
#pragma unroll
        for (int i = 0; i < 2; ++i) {
            gld_lds16(asrc[i] + kofs, As + bufi * 8192 + aoff[i]);
            gld_lds16(bsrc[i] + kofs, Bs + bufi * 8192 + aoff[i]);
        }
    };

    const int nsteps = Kslice >> 6;
    stage(0, 0);
    asm volatile("s_waitcnt vmcnt(0)" ::: "memory");
    __builtin_amdgcn_s_barrier();

    int cur = 0;
    for (int t = 0; t < nsteps; ++t) {
        if (t + 1 < nsteps) stage(cur ^ 1, (t + 1) * 64);
        const u16* Ab = As + cur * 8192;
        const u16* Bb = Bs + cur * 8192;
#pragma unroll
        for (int kk = 0; kk < 2; ++kk) {
            bf16x8 a[4], b[2];
#pragma unroll
            for (int i = 0; i < 4; ++i) {
                int row = wr * 64 + i * 16 + l15;
                a[i] = *(const bf16x8*)&Ab[row * 64 + ((kk * 4 + lg) ^ (row & 7)) * 8];
            }
#pragma unroll
            for (int j = 0; j < 2; ++j) {
                int row = wc * 32 + j * 16 + l15;
                b[j] = *(const bf16x8*)&Bb[row * 64 + ((kk * 4 + lg) ^ (row & 7)) * 8];
            }
#pragma unroll
            for (int i = 0; i < 4; ++i)
#pragma unroll
                for (int j = 0; j < 2; ++j)
                    acc[i][j] = __builtin_amdgcn_mfma_f32_16x16x32_bf16(a[i], b[j], acc[i][j], 0, 0, 0);
        }
        asm volatile("s_waitcnt vmcnt(0)" ::: "memory");
        __builtin_amdgcn_s_barrier();
        cur ^= 1;
    }

#pragma unroll
    for (int i = 0; i < 4; ++i)
#pragma unroll
        for (int j = 0; j < 2; ++j)
#pragma unroll
            for (int r = 0; r < 4; ++r) {
                int m = m0 + wr * 64 + i * 16 + lg * 4 + r;
                int n = n0 + wc * 32 + j * 16 + l15;
                if (n < N) {
                    if (OUT_BF16)
                        ((u16*)Cv)[(long)m * N + n] = f2bf(acc[i][j][r]);
                    else
                        ((float*)Cv)[(long)blockIdx.z * M * N + (long)m * N + n] = acc[i][j][r];
                }
            }
}

// ---------------- sum split-K partials (fp32), x4 vectorized ----------------
__global__ __launch_bounds__(256) void reduce_parts(const float* __restrict__ parts,
                                                    float* __restrict__ out,
                                                    int nparts, long mn) {
    long i = ((long)blockIdx.x * 256 + threadIdx.x) * 4;
    long stride = (long)gridDim.x * 256 * 4;
    for (; i < mn; i += stride) {
        float4 s = *(const float4*)(parts + i);
        for (int p = 1; p < nparts; ++p) {
            float4 v = *(const float4*)(parts + (long)p * mn + i);
            s.x += v.x; s.y += v.y; s.z += v.z; s.w += v.w;
        }
        *(float4*)(out + i) = s;
    }
}

// ---------------- RMSNorm (row-wise): y = x * rsqrt(mean(x^2)+eps) * w ----------------
__global__ __launch_bounds__(256) void rmsnorm_kernel(const float* __restrict__ x,
                                                      const float* __restrict__ w,
                                                      u16* __restrict__ y,
                                                      int stride, int norm_len) {
    const int row = blockIdx.x;
    const float* xr = x + (long)row * stride;
    float ss = 0.f;
    for (int i = threadIdx.x; i < norm_len; i += 256) {
        float v = xr[i];
        ss += v * v;
    }
#pragma unroll
    for (int off = 32; off > 0; off >>= 1) ss += __shfl_down(ss, off);
    __shared__ float partial[4];
    if ((threadIdx.x & 63) == 0) partial[threadIdx.x >> 6] = ss;
    __syncthreads();
    float tot = partial[0] + partial[1] + partial[2] + partial[3];
    float rs = 1.0f / sqrtf(tot / (float)norm_len + RMS_EPS);
    u16* yr = y + (long)row * norm_len;
    for (int i = threadIdx.x; i < norm_len; i += 256) yr[i] = f2bf(xr[i] * rs * w[i]);
}

// ---------------- RoPE tables (fp32): cos/sin[s][i], i<32 ----------------
__global__ void rope_tables(float* __restrict__ cos_t, float* __restrict__ sin_t) {
    int s = blockIdx.x;
    int i = threadIdx.x;  // 32 threads
    float invf = powf(10000.0f, -((float)(2 * i) / 64.0f));
    float ang = (float)s * invf;
    cos_t[s * 32 + i] = cosf(ang);
    sin_t[s * 32 + i] = sinf(ang);
}

// ---------------- RoPE on q_r, in-place on q_cr (bf16) ----------------
__global__ void rope_q(u16* __restrict__ q_cr, const float* __restrict__ cos_t,
                       const float* __restrict__ sin_t) {
    int s = blockIdx.x;
    int h = blockIdx.y * 2 + (threadIdx.x >> 5);
    int i = threadIdx.x & 31;
    u16* base = q_cr + (s * (NHEAD * 192) + h * 192 + QKD);
    float x1 = bf2f(base[i]);
    float x2 = bf2f(base[i + 32]);
    float c = cos_t[s * 32 + i], sn = sin_t[s * 32 + i];
    base[i]      = f2bf(x1 * c - x2 * sn);
    base[i + 32] = f2bf(x2 * c + x1 * sn);
}

// ---------------- RoPE on k_r (from fp32 ckv_kr cols 512..576) -> bf16 kr ----------------
__global__ void rope_k(const float* __restrict__ ckv_kr, const float* __restrict__ cos_t,
                       const float* __restrict__ sin_t, u16* __restrict__ kr) {
    int s = blockIdx.x;
    int i = threadIdx.x;  // 64 threads; first 32 active
    if (i < 32) {
        const float* base = ckv_kr + (s * 576 + 512);
        float x1 = base[i], x2 = base[i + 32];
        float c = cos_t[s * 32 + i], sn = sin_t[s * 32 + i];
        kr[s * 64 + i]      = f2bf(x1 * c - x2 * sn);
        kr[s * 64 + i + 32] = f2bf(x2 * c + x1 * sn);
    }
}

// ---------------- build vT[h][dv][s] from kv[s][h*256+128+dv] ----------------
__global__ __launch_bounds__(256) void build_vt(const u16* __restrict__ kv,
                                                u16* __restrict__ vT) {
    __shared__ u16 vtile[64][136];  // 272B row stride (16B aligned)
    const int h = blockIdx.x, sb = blockIdx.y, s0 = sb * 64;
    const int tid = threadIdx.x;
#pragma unroll
    for (int it = 0; it < 4; ++it) {
        int c = it * 256 + tid;
        int row = c >> 4;
        int off8 = (c & 15) * 8;
        *(u16x8*)&vtile[row][off8] =
            *(const u16x8*)&kv[(s0 + row) * 32768 + h * 256 + 128 + off8];
    }
    __syncthreads();
    const int sl = tid & 63;
    const int dvb = tid >> 6;  // 0..3
#pragma unroll
    for (int it = 0; it < 32; ++it) {
        int dv = dvb + it * 4;
        vT[(h * 128 + dv) * 1024 + s0 + sl] = vtile[sl][dv];
    }
}

// ---------------- flash attention: 1 block = 128 queries x 1 head, 8 waves ----------------
// T14 async-STAGE (reg prefetch of next tile under compute) + T5 setprio
// around MFMA clusters. p_lds is wave-private -> no barrier after P-write.
__global__ __launch_bounds__(512) void mla_attn(const u16* __restrict__ q_cr,
                                                const u16* __restrict__ kv,
                                                const u16* __restrict__ kr,
                                                const u16* __restrict__ vT,
                                                u16* __restrict__ o_g) {
    __shared__ u16 ks[64][200];        // 64 keys x 192 dims (+pad)
    __shared__ u16 vts[128][72];       // 128 dv x 64 k (+pad)
    __shared__ u16 p_lds[8][16][72];   // per wave: 16 q x 64 k (+pad)
    const int qb = blockIdx.x, h = blockIdx.y;
    const int s0q = qb * 128;
    const int tid = threadIdx.x, lane = tid & 63, w = tid >> 6;
    const int l15 = lane & 15, lg = lane >> 4;
    const float scale = 0.07216878364870323f;  // 1/sqrt(192)

    // Q in registers, A-fragment layout (row = l15, k contiguous per lg group)
    bf16x8 qreg[6];
    {
        const int qrow = s0q + w * 16 + l15;
#pragma unroll
        for (int kk = 0; kk < 6; ++kk)
            qreg[kk] = *(const bf16x8*)&q_cr[qrow * (NHEAD * 192) + h * 192 + kk * 32 + lg * 8];
    }

    // staging-index precompute (512 threads cover: K 2x, kr 1x, V 2x u16x8 each)
    const int krow0 = tid >> 4,           koff0 = (tid & 15) * 8;
    const int krow1 = (512 + tid) >> 4,   koff1 = ((512 + tid) & 15) * 8;
    const int rrow  = tid >> 3,           roff  = (tid & 7) * 8;
    const int vdv0  = tid >> 3,           voff0 = (tid & 7) * 8;
    const int vdv1  = (512 + tid) >> 3,   voff1 = ((512 + tid) & 7) * 8;
    const u16* kvp = kv + h * 256;
    const u16* vtp = vT + (long)(h * 128) * 1024;

    u16x8 kreg0, kreg1, krreg, vreg0, vreg1;
    auto load_tile = [&](int s0k) {
        kreg0 = *(const u16x8*)&kvp[(long)(s0k + krow0) * 32768 + koff0];
        kreg1 = *(const u16x8*)&kvp[(long)(s0k + krow1) * 32768 + koff1];
        krreg = *(const u16x8*)&kr[(s0k + rrow) * 64 + roff];
        vreg0 = *(const u16x8*)&vtp[(long)vdv0 * 1024 + s0k + voff0];
        vreg1 = *(const u16x8*)&vtp[(long)vdv1 * 1024 + s0k + voff1];
    };

    f32x4 o_acc[8];
    const f32x4 z = {0.f, 0.f, 0.f, 0.f};
#pragma unroll
    for (int d = 0; d < 8; ++d) o_acc[d] = z;
    float m_r[4], l_r[4];
#pragma unroll
    for (int r = 0; r < 4; ++r) { m_r[r] = -1e30f; l_r[r] = 0.f; }

    load_tile(0);

    for (int kt = 0; kt < 16; ++kt) {
        __syncthreads();   // prev tile's readers done
        *(u16x8*)&ks[krow0][koff0]      = kreg0;
        *(u16x8*)&ks[krow1][koff1]      = kreg1;
        *(u16x8*)&ks[rrow][128 + roff]  = krreg;
        *(u16x8*)&vts[vdv0][voff0]      = vreg0;
        *(u16x8*)&vts[vdv1][voff1]      = vreg1;
        __syncthreads();   // tile staged
        if (kt + 1 < 16) load_tile((kt + 1) * 64);   // async: hides under compute

        // QK^T : S-frags (16 q x 64 keys per wave)
        f32x4 sf[4];
#pragma unroll
        for (int j = 0; j < 4; ++j) sf[j] = z;
        __builtin_amdgcn_s_setprio(1);
#pragma unroll
        for (int kk = 0; kk < 6; ++kk) {
            bf16x8 a = qreg[kk];
#pragma unroll
            for (int j = 0; j < 4; ++j) {
                bf16x8 b = *(const bf16x8*)&ks[j * 16 + l15][kk * 32 + lg * 8];
                sf[j] = __builtin_amdgcn_mfma_f32_16x16x32_bf16(a, b, sf[j], 0, 0, 0);
            }
        }
        __builtin_amdgcn_s_setprio(0);

        // online softmax (rows live in C-layout: row=(lg)*4+r, col=j*16+l15)
        float p[4][4];
        float alpha[4];
#pragma unroll
        for (int r = 0; r < 4; ++r) {
            float mx = fmaxf(fmaxf(sf[0][r], sf[1][r]), fmaxf(sf[2][r], sf[3][r]));
#pragma unroll
            for (int off = 1; off < 16; off <<= 1) mx = fmaxf(mx, __shfl_xor(mx, off));
            mx *= scale;
            float mnew = fmaxf(m_r[r], mx);
            alpha[r] = __expf(m_r[r] - mnew);
            float rs = 0.f;
#pragma unroll
            for (int j = 0; j < 4; ++j) {
                float pv = __expf(sf[j][r] * scale - mnew);
                p[j][r] = pv;
                rs += pv;
            }
#pragma unroll
            for (int off = 1; off < 16; off <<= 1) rs += __shfl_xor(rs, off);
            l_r[r] = l_r[r] * alpha[r] + rs;
            m_r[r] = mnew;
        }
#pragma unroll
        for (int d = 0; d < 8; ++d)
#pragma unroll
            for (int r = 0; r < 4; ++r) o_acc[d][r] *= alpha[r];

        // P -> LDS (wave-private; no block barrier needed)
#pragma unroll
        for (int j = 0; j < 4; ++j)
#pragma unroll
            for (int r = 0; r < 4; ++r)
                p_lds[w][lg * 4 + r][j * 16 + l15] = f2bf(p[j][r]);

        // PV: O += P @ V
        __builtin_amdgcn_s_setprio(1);
#pragma unroll
        for (int kk2 = 0; kk2 < 2; ++kk2) {
            bf16x8 a = *(const bf16x8*)&p_lds[w][l15][kk2 * 32 + lg * 8];
#pragma unroll
            for (int d = 0; d < 8; ++d) {
                bf16x8 b = *(const bf16x8*)&vts[d * 16 + l15][kk2 * 32 + lg * 8];
                o_acc[d] = __builtin_amdgcn_mfma_f32_16x16x32_bf16(a, b, o_acc[d], 0, 0, 0);
            }
        }
        __builtin_amdgcn_s_setprio(0);
    }

    // epilogue: divide by l, store bf16 o[s][h*128+dv]
#pragma unroll
    for (int d = 0; d < 8; ++d)
#pragma unroll
        for (int r = 0; r < 4; ++r) {
            int srow = s0q + w * 16 + lg * 4 + r;
            float v = o_acc[d][r] / l_r[r];
            o_g[srow * 16384 + h * 128 + d * 16 + l15] = f2bf(v);
        }
}

// ---------------- host launcher ----------------
extern "C" void kernel_launch(void* const* d_in, const int* in_sizes, int n_in,
                              void* d_out, int out_size, void* d_ws, size_t ws_size,
                              hipStream_t stream) {
    const float* hs        = (const float*)d_in[0];
    const float* w_q_down  = (const float*)d_in[1];
    const float* q_norm_w  = (const float*)d_in[2];
    const float* w_q_up    = (const float*)d_in[3];
    const float* w_kv_down = (const float*)d_in[4];
    const float* kv_norm_w = (const float*)d_in[5];
    const float* w_kv_up   = (const float*)d_in[6];
    const float* w_out     = (const float*)d_in[7];
    float* out = (float*)d_out;
    char* ws = (char*)d_ws;

    // ---- workspace layout (contiguous front region is reused for w_out bf16) ----
    const size_t SZ_HS   = (size_t)SEQ * HIDN * 2;            // 14,680,064
    const size_t SZ_KV   = (size_t)SEQ * 32768 * 2;           // 67,108,864
    const size_t SZ_QCR  = (size_t)SEQ * (NHEAD * 192) * 2;   // 50,331,648
    const size_t SZ_VT   = (size_t)NHEAD * 128 * 1024 * 2;    // 33,554,432
    const size_t SZ_WB   = (size_t)24576 * 1536 * 2;          // 75,497,472 (max of small weights)
    const size_t SZ_CQ   = (size_t)SEQ * QLRANK * 4;
    const size_t SZ_CQN  = (size_t)SEQ * QLRANK * 2;
    const size_t SZ_CKV  = (size_t)SEQ * 576 * 4;
    const size_t SZ_CKVN = (size_t)SEQ * KVLRANK * 2;
    const size_t SZ_KR   = (size_t)SEQ * 64 * 2;
    const size_t SZ_OG   = (size_t)SEQ * 16384 * 2;
    const size_t SZ_TAB  = (size_t)SEQ * 32 * 4;

    size_t off = 0;
    u16* hs_bf  = (u16*)(ws + off); off += SZ_HS;
    u16* kvb    = (u16*)(ws + off); off += SZ_KV;
    u16* q_cr   = (u16*)(ws + off); off += SZ_QCR;
    u16* vT     = (u16*)(ws + off); off += SZ_VT;
    u16* W_BUF  = (u16*)(ws + off); off += SZ_WB;
    // split-K partials for c_q/kv_down alias upper W_BUF region (+32MB; weight
    // there is <32MB while these gemms run).
    float* parts = (float*)((char*)W_BUF + 33554432);
    // w_out bf16 (234,881,024 B) aliases [ws .. 235MB), all dead by then
    u16* wout_bf = (u16*)ws;
    float* c_q    = (float*)(ws + off); off += SZ_CQ;
    u16* cq_n     = (u16*)(ws + off); off += SZ_CQN;
    float* ckv_kr = (float*)(ws + off); off += SZ_CKV;
    u16* ckv_n    = (u16*)(ws + off); off += SZ_CKVN;
    u16* kr       = (u16*)(ws + off); off += SZ_KR;
    u16* o_g      = (u16*)(ws + off); off += SZ_OG;
    float* cos_t  = (float*)(ws + off); off += SZ_TAB;
    float* sin_t  = (float*)(ws + off); off += SZ_TAB;
    (void)in_sizes; (void)n_in; (void)out_size; (void)ws_size;

    rope_tables<<<dim3(SEQ), dim3(32), 0, stream>>>(cos_t, sin_t);
    f32_to_bf16<<<2048, 256, 0, stream>>>(hs, hs_bf, (long)SEQ * HIDN);

    // c_q = hs @ w_q_down^T   (split-K x4: 7168 = 4 x 1792; per-slice grid 96 %8==0)
    f32_to_bf16<<<2048, 256, 0, stream>>>(w_q_down, W_BUF, (long)QLRANK * HIDN);
    gemm_bt<0><<<dim3(QLRANK / 128, SEQ / 128, 4), 512, 0, stream>>>(hs_bf, W_BUF, parts, SEQ, QLRANK, HIDN / 4, HIDN);
    reduce_parts<<<1024, 256, 0, stream>>>(parts, c_q, 4, (long)SEQ * QLRANK);
    rmsnorm_kernel<<<SEQ, 256, 0, stream>>>(c_q, q_norm_w, cq_n, QLRANK, QLRANK);

    // q_cr = rmsnorm(c_q) @ w_q_up^T   (grid 1536 %8==0)
    f32_to_bf16<<<2048, 256, 0, stream>>>(w_q_up, W_BUF, (long)24576 * QLRANK);
    gemm_bt<1><<<dim3(24576 / 128, SEQ / 128), 512, 0, stream>>>(cq_n, W_BUF, q_cr, SEQ, 24576, QLRANK, QLRANK);

    // ckv_kr = hs @ w_kv_down^T   (split-K x8; per-slice grid 40 %8==0)
    f32_to_bf16<<<2048, 256, 0, stream>>>(w_kv_down, W_BUF, (long)576 * HIDN);
    gemm_bt<0><<<dim3(5, SEQ / 128, 8), 512, 0, stream>>>(hs_bf, W_BUF, parts, SEQ, 576, HIDN / 8, HIDN);
    reduce_parts<<<1024, 256, 0, stream>>>(parts, ckv_kr, 8, (long)SEQ * 576);
    rmsnorm_kernel<<<SEQ, 256, 0, stream>>>(ckv_kr, kv_norm_w, ckv_n, 576, KVLRANK);
    rope_k<<<SEQ, 64, 0, stream>>>(ckv_kr, cos_t, sin_t, kr);

    // kv = rmsnorm(c_kv) @ w_kv_up^T   (grid 2048 %8==0)
    f32_to_bf16<<<2048, 256, 0, stream>>>(w_kv_up, W_BUF, (long)32768 * KVLRANK);
    gemm_bt<1><<<dim3(32768 / 128, SEQ / 128), 512, 0, stream>>>(ckv_n, W_BUF, kvb, SEQ, 32768, KVLRANK, KVLRANK);

    rope_q<<<dim3(SEQ, NHEAD / 2), 64, 0, stream>>>(q_cr, cos_t, sin_t);
    build_vt<<<dim3(NHEAD, SEQ / 64), 256, 0, stream>>>(kvb, vT);

    mla_attn<<<dim3(SEQ / 128, NHEAD), 512, 0, stream>>>(q_cr, kvb, kr, vT, o_g);

    // out = o @ w_out^T   (no split-K; grid 448 %8==0)
    f32_to_bf16<<<4096, 256, 0, stream>>>(w_out, wout_bf, (long)HIDN * 16384);
    gemm_bt<0><<<dim3(HIDN / 128, SEQ / 128), 512, 0, stream>>>(o_g, wout_bf, out, SEQ, HIDN, 16384, 16384);
}

// Round 10
// 978.249 us; speedup vs baseline: 1.4748x; 1.0398x over previous
//
#include <hip/hip_runtime.h>
#include <hip/hip_bf16.h>
#include <math.h>

// ---- problem constants ----
#define HIDN 7168
#define NHEAD 128
#define QLRANK 1536
#define KVLRANK 512
#define QKD 128
#define VHD 128
#define RHD 64
#define SEQ 1024
#define RMS_EPS 1.1920929e-07f

typedef unsigned short u16;
typedef __attribute__((ext_vector_type(8))) short bf16x8;
typedef __attribute__((ext_vector_type(4))) float f32x4;
typedef __attribute__((ext_vector_type(8))) unsigned short u16x8;

__device__ __forceinline__ u16 f2bf(float f) {
    unsigned int u = __float_as_uint(f);
    unsigned int r = (u + 0x7FFFu + ((u >> 16) & 1u)) >> 16;
    return (u16)r;
}
__device__ __forceinline__ float bf2f(u16 v) {
    return __uint_as_float(((unsigned int)v) << 16);
}

// async global->LDS, 16B per lane. LDS dest is wave-uniform base + lane*16.
__device__ __forceinline__ void gld_lds16(const u16* g, u16* l) {
    __builtin_amdgcn_global_load_lds(
        (const __attribute__((address_space(1))) unsigned int*)g,
        (__attribute__((address_space(3))) unsigned int*)l,
        16, 0, 0);
}

// ---------------- fp32 -> bf16 conversion (x8 vectorized) ----------------
__global__ __launch_bounds__(256) void f32_to_bf16(const float* __restrict__ in,
                                                   u16* __restrict__ out, long n) {
    long i = ((long)blockIdx.x * blockDim.x + threadIdx.x) * 8;
    long stride = (long)gridDim.x * blockDim.x * 8;
    for (; i < n; i += stride) {
        float4 a = *(const float4*)(in + i);
        float4 b = *(const float4*)(in + i + 4);
        u16x8 o;
        o[0] = f2bf(a.x); o[1] = f2bf(a.y); o[2] = f2bf(a.z); o[3] = f2bf(a.w);
        o[4] = f2bf(b.x); o[5] = f2bf(b.y); o[6] = f2bf(b.z); o[7] = f2bf(b.w);
        *(u16x8*)(out + i) = o;
    }
}

// ---------------- generic GEMM: C[m][n] = sum_k A[m][k]*B[n][k] ----------------
// r9 structure WITHOUT the XCD remap: natural dispatch order already gives
// optimal XCD affinity when gridDim.x%8==0 (blocks sharing a B-strip have
// lin%8 = x%8 -> same XCD; the 4MB bf16 B-strip fits that XCD's 4MB L2, so
// B is fetched from HBM once; r9's swizzle broke this: FETCH 336->940MB).
// 128x128 tile, BK=64, 8 waves (512 thr), per-wave output 64x32 (acc 4x2).
// LDS 64 KiB dbuf -> 2 blocks/CU x 8 waves = 4 waves/SIMD TLP.
// Staging: global_load_lds(16), coalesced row-grouped source map + XOR chunk
// swizzle (0 bank conflicts). One vmcnt(0)+s_barrier per K-step.
// Split-K via blockIdx.z: fp32 partials at Cv + z*M*N (OUT_BF16=0 only).
template <int OUT_BF16>
__global__ __launch_bounds__(512) void gemm_bt(const u16* __restrict__ A,
                                               const u16* __restrict__ B,
                                               void* __restrict__ Cv,
                                               int M, int N, int Kslice, long ldk) {
    __shared__ u16 As[2 * 128 * 64];   // 2 x 16 KiB
    __shared__ u16 Bs[2 * 128 * 64];
    const int tid = threadIdx.x;
    const int lane = tid & 63;
    const int w = tid >> 6;            // 0..7
    const int wr = w >> 2, wc = w & 3; // wave grid 2M x 4N
    const int l15 = lane & 15, lg = lane >> 4;
    const int n0 = blockIdx.x * 128;
    const int m0 = blockIdx.y * 128;
    const long kbase = (long)blockIdx.z * Kslice;

    // staging: 2 issues per wave per matrix; each issue = 8 rows x 64 cols.
    // lane covers row (base + lane>>3), 16B chunk p=lane&7; global chunk p^(r&7).
    const u16* asrc[2];
    const u16* bsrc[2];
    int aoff[2];
#pragma unroll
    for (int i = 0; i < 2; ++i) {
        int r = (w * 2 + i) * 8 + (lane >> 3);
        int gc = (lane & 7) ^ (r & 7);
        asrc[i] = A + (long)(m0 + r) * ldk + kbase + gc * 8;
        int br = n0 + r; if (br >= N) br = N - 1;
        bsrc[i] = B + (long)br * ldk + kbase + gc * 8;
        aoff[i] = (w * 2 + i) * 512;
    }

    f32x4 acc[4][2];
    const f32x4 z = {0.f, 0.f, 0.f, 0.f};
#pragma unroll
    for (int i = 0; i < 4; ++i)
#pragma unroll
        for (int j = 0; j < 2; ++j) acc[i][j] = z;

    auto stage = [&](int bufi, int kofs) {
#pragma unroll
        for (int i = 0; i < 2; ++i) {
            gld_lds16(asrc[i] + kofs, As + bufi * 8192 + aoff[i]);
            gld_lds16(bsrc[i] + kofs, Bs + bufi * 8192 + aoff[i]);
        }
    };

    const int nsteps = Kslice >> 6;
    stage(0, 0);
    asm volatile("s_waitcnt vmcnt(0)" ::: "memory");
    __builtin_amdgcn_s_barrier();

    int cur = 0;
    for (int t = 0; t < nsteps; ++t) {
        if (t + 1 < nsteps) stage(cur ^ 1, (t + 1) * 64);
        const u16* Ab = As + cur * 8192;
        const u16* Bb = Bs + cur * 8192;
#pragma unroll
        for (int kk = 0; kk < 2; ++kk) {
            bf16x8 a[4], b[2];
#pragma unroll
            for (int i = 0; i < 4; ++i) {
                int row = wr * 64 + i * 16 + l15;
                a[i] = *(const bf16x8*)&Ab[row * 64 + ((kk * 4 + lg) ^ (row & 7)) * 8];
            }
#pragma unroll
            for (int j = 0; j < 2; ++j) {
                int row = wc * 32 + j * 16 + l15;
                b[j] = *(const bf16x8*)&Bb[row * 64 + ((kk * 4 + lg) ^ (row & 7)) * 8];
            }
#pragma unroll
            for (int i = 0; i < 4; ++i)
#pragma unroll
                for (int j = 0; j < 2; ++j)
                    acc[i][j] = __builtin_amdgcn_mfma_f32_16x16x32_bf16(a[i], b[j], acc[i][j], 0, 0, 0);
        }
        asm volatile("s_waitcnt vmcnt(0)" ::: "memory");
        __builtin_amdgcn_s_barrier();
        cur ^= 1;
    }

#pragma unroll
    for (int i = 0; i < 4; ++i)
#pragma unroll
        for (int j = 0; j < 2; ++j)
#pragma unroll
            for (int r = 0; r < 4; ++r) {
                int m = m0 + wr * 64 + i * 16 + lg * 4 + r;
                int n = n0 + wc * 32 + j * 16 + l15;
                if (n < N) {
                    if (OUT_BF16)
                        ((u16*)Cv)[(long)m * N + n] = f2bf(acc[i][j][r]);
                    else
                        ((float*)Cv)[(long)blockIdx.z * M * N + (long)m * N + n] = acc[i][j][r];
                }
            }
}

// ---------------- sum split-K partials (fp32), x4 vectorized ----------------
__global__ __launch_bounds__(256) void reduce_parts(const float* __restrict__ parts,
                                                    float* __restrict__ out,
                                                    int nparts, long mn) {
    long i = ((long)blockIdx.x * 256 + threadIdx.x) * 4;
    long stride = (long)gridDim.x * 256 * 4;
    for (; i < mn; i += stride) {
        float4 s = *(const float4*)(parts + i);
        for (int p = 1; p < nparts; ++p) {
            float4 v = *(const float4*)(parts + (long)p * mn + i);
            s.x += v.x; s.y += v.y; s.z += v.z; s.w += v.w;
        }
        *(float4*)(out + i) = s;
    }
}

// ---------------- RMSNorm (row-wise): y = x * rsqrt(mean(x^2)+eps) * w ----------------
__global__ __launch_bounds__(256) void rmsnorm_kernel(const float* __restrict__ x,
                                                      const float* __restrict__ w,
                                                      u16* __restrict__ y,
                                                      int stride, int norm_len) {
    const int row = blockIdx.x;
    const float* xr = x + (long)row * stride;
    float ss = 0.f;
    for (int i = threadIdx.x; i < norm_len; i += 256) {
        float v = xr[i];
        ss += v * v;
    }
#pragma unroll
    for (int off = 32; off > 0; off >>= 1) ss += __shfl_down(ss, off);
    __shared__ float partial[4];
    if ((threadIdx.x & 63) == 0) partial[threadIdx.x >> 6] = ss;
    __syncthreads();
    float tot = partial[0] + partial[1] + partial[2] + partial[3];
    float rs = 1.0f / sqrtf(tot / (float)norm_len + RMS_EPS);
    u16* yr = y + (long)row * norm_len;
    for (int i = threadIdx.x; i < norm_len; i += 256) yr[i] = f2bf(xr[i] * rs * w[i]);
}

// ---------------- RoPE tables (fp32): cos/sin[s][i], i<32 ----------------
__global__ void rope_tables(float* __restrict__ cos_t, float* __restrict__ sin_t) {
    int s = blockIdx.x;
    int i = threadIdx.x;  // 32 threads
    float invf = powf(10000.0f, -((float)(2 * i) / 64.0f));
    float ang = (float)s * invf;
    cos_t[s * 32 + i] = cosf(ang);
    sin_t[s * 32 + i] = sinf(ang);
}

// ---------------- RoPE on q_r, in-place on q_cr (bf16) ----------------
__global__ void rope_q(u16* __restrict__ q_cr, const float* __restrict__ cos_t,
                       const float* __restrict__ sin_t) {
    int s = blockIdx.x;
    int h = blockIdx.y * 2 + (threadIdx.x >> 5);
    int i = threadIdx.x & 31;
    u16* base = q_cr + (s * (NHEAD * 192) + h * 192 + QKD);
    float x1 = bf2f(base[i]);
    float x2 = bf2f(base[i + 32]);
    float c = cos_t[s * 32 + i], sn = sin_t[s * 32 + i];
    base[i]      = f2bf(x1 * c - x2 * sn);
    base[i + 32] = f2bf(x2 * c + x1 * sn);
}

// ---------------- RoPE on k_r (from fp32 ckv_kr cols 512..576) -> bf16 kr ----------------
__global__ void rope_k(const float* __restrict__ ckv_kr, const float* __restrict__ cos_t,
                       const float* __restrict__ sin_t, u16* __restrict__ kr) {
    int s = blockIdx.x;
    int i = threadIdx.x;  // 64 threads; first 32 active
    if (i < 32) {
        const float* base = ckv_kr + (s * 576 + 512);
        float x1 = base[i], x2 = base[i + 32];
        float c = cos_t[s * 32 + i], sn = sin_t[s * 32 + i];
        kr[s * 64 + i]      = f2bf(x1 * c - x2 * sn);
        kr[s * 64 + i + 32] = f2bf(x2 * c + x1 * sn);
    }
}

// ---------------- build vT[h][dv][s] from kv[s][h*256+128+dv] ----------------
__global__ __launch_bounds__(256) void build_vt(const u16* __restrict__ kv,
                                                u16* __restrict__ vT) {
    __shared__ u16 vtile[64][136];  // 272B row stride (16B aligned)
    const int h = blockIdx.x, sb = blockIdx.y, s0 = sb * 64;
    const int tid = threadIdx.x;
#pragma unroll
    for (int it = 0; it < 4; ++it) {
        int c = it * 256 + tid;
        int row = c >> 4;
        int off8 = (c & 15) * 8;
        *(u16x8*)&vtile[row][off8] =
            *(const u16x8*)&kv[(s0 + row) * 32768 + h * 256 + 128 + off8];
    }
    __syncthreads();
    const int sl = tid & 63;
    const int dvb = tid >> 6;  // 0..3
#pragma unroll
    for (int it = 0; it < 32; ++it) {
        int dv = dvb + it * 4;
        vT[(h * 128 + dv) * 1024 + s0 + sl] = vtile[sl][dv];
    }
}

// ---------------- flash attention: 1 block = 128 queries x 1 head, 8 waves ----------------
// T14 async-STAGE (reg prefetch of next tile under compute) + T5 setprio
// around MFMA clusters. p_lds is wave-private -> no barrier after P-write.
__global__ __launch_bounds__(512) void mla_attn(const u16* __restrict__ q_cr,
                                                const u16* __restrict__ kv,
                                                const u16* __restrict__ kr,
                                                const u16* __restrict__ vT,
                                                u16* __restrict__ o_g) {
    __shared__ u16 ks[64][200];        // 64 keys x 192 dims (+pad)
    __shared__ u16 vts[128][72];       // 128 dv x 64 k (+pad)
    __shared__ u16 p_lds[8][16][72];   // per wave: 16 q x 64 k (+pad)
    const int qb = blockIdx.x, h = blockIdx.y;
    const int s0q = qb * 128;
    const int tid = threadIdx.x, lane = tid & 63, w = tid >> 6;
    const int l15 = lane & 15, lg = lane >> 4;
    const float scale = 0.07216878364870323f;  // 1/sqrt(192)

    // Q in registers, A-fragment layout (row = l15, k contiguous per lg group)
    bf16x8 qreg[6];
    {
        const int qrow = s0q + w * 16 + l15;
#pragma unroll
        for (int kk = 0; kk < 6; ++kk)
            qreg[kk] = *(const bf16x8*)&q_cr[qrow * (NHEAD * 192) + h * 192 + kk * 32 + lg * 8];
    }

    // staging-index precompute (512 threads cover: K 2x, kr 1x, V 2x u16x8 each)
    const int krow0 = tid >> 4,           koff0 = (tid & 15) * 8;
    const int krow1 = (512 + tid) >> 4,   koff1 = ((512 + tid) & 15) * 8;
    const int rrow  = tid >> 3,           roff  = (tid & 7) * 8;
    const int vdv0  = tid >> 3,           voff0 = (tid & 7) * 8;
    const int vdv1  = (512 + tid) >> 3,   voff1 = ((512 + tid) & 7) * 8;
    const u16* kvp = kv + h * 256;
    const u16* vtp = vT + (long)(h * 128) * 1024;

    u16x8 kreg0, kreg1, krreg, vreg0, vreg1;
    auto load_tile = [&](int s0k) {
        kreg0 = *(const u16x8*)&kvp[(long)(s0k + krow0) * 32768 + koff0];
        kreg1 = *(const u16x8*)&kvp[(long)(s0k + krow1) * 32768 + koff1];
        krreg = *(const u16x8*)&kr[(s0k + rrow) * 64 + roff];
        vreg0 = *(const u16x8*)&vtp[(long)vdv0 * 1024 + s0k + voff0];
        vreg1 = *(const u16x8*)&vtp[(long)vdv1 * 1024 + s0k + voff1];
    };

    f32x4 o_acc[8];
    const f32x4 z = {0.f, 0.f, 0.f, 0.f};
#pragma unroll
    for (int d = 0; d < 8; ++d) o_acc[d] = z;
    float m_r[4], l_r[4];
#pragma unroll
    for (int r = 0; r < 4; ++r) { m_r[r] = -1e30f; l_r[r] = 0.f; }

    load_tile(0);

    for (int kt = 0; kt < 16; ++kt) {
        __syncthreads();   // prev tile's readers done
        *(u16x8*)&ks[krow0][koff0]      = kreg0;
        *(u16x8*)&ks[krow1][koff1]      = kreg1;
        *(u16x8*)&ks[rrow][128 + roff]  = krreg;
        *(u16x8*)&vts[vdv0][voff0]      = vreg0;
        *(u16x8*)&vts[vdv1][voff1]      = vreg1;
        __syncthreads();   // tile staged
        if (kt + 1 < 16) load_tile((kt + 1) * 64);   // async: hides under compute

        // QK^T : S-frags (16 q x 64 keys per wave)
        f32x4 sf[4];
#pragma unroll
        for (int j = 0; j < 4; ++j) sf[j] = z;
        __builtin_amdgcn_s_setprio(1);
#pragma unroll
        for (int kk = 0; kk < 6; ++kk) {
            bf16x8 a = qreg[kk];
#pragma unroll
            for (int j = 0; j < 4; ++j) {
                bf16x8 b = *(const bf16x8*)&ks[j * 16 + l15][kk * 32 + lg * 8];
                sf[j] = __builtin_amdgcn_mfma_f32_16x16x32_bf16(a, b, sf[j], 0, 0, 0);
            }
        }
        __builtin_amdgcn_s_setprio(0);

        // online softmax (rows live in C-layout: row=(lg)*4+r, col=j*16+l15)
        float p[4][4];
        float alpha[4];
#pragma unroll
        for (int r = 0; r < 4; ++r) {
            float mx = fmaxf(fmaxf(sf[0][r], sf[1][r]), fmaxf(sf[2][r], sf[3][r]));
#pragma unroll
            for (int off = 1; off < 16; off <<= 1) mx = fmaxf(mx, __shfl_xor(mx, off));
            mx *= scale;
            float mnew = fmaxf(m_r[r], mx);
            alpha[r] = __expf(m_r[r] - mnew);
            float rs = 0.f;
#pragma unroll
            for (int j = 0; j < 4; ++j) {
                float pv = __expf(sf[j][r] * scale - mnew);
                p[j][r] = pv;
                rs += pv;
            }
#pragma unroll
            for (int off = 1; off < 16; off <<= 1) rs += __shfl_xor(rs, off);
            l_r[r] = l_r[r] * alpha[r] + rs;
            m_r[r] = mnew;
        }
#pragma unroll
        for (int d = 0; d < 8; ++d)
#pragma unroll
            for (int r = 0; r < 4; ++r) o_acc[d][r] *= alpha[r];

        // P -> LDS (wave-private; no block barrier needed)
#pragma unroll
        for (int j = 0; j < 4; ++j)
#pragma unroll
            for (int r = 0; r < 4; ++r)
                p_lds[w][lg * 4 + r][j * 16 + l15] = f2bf(p[j][r]);

        // PV: O += P @ V
        __builtin_amdgcn_s_setprio(1);
#pragma unroll
        for (int kk2 = 0; kk2 < 2; ++kk2) {
            bf16x8 a = *(const bf16x8*)&p_lds[w][l15][kk2 * 32 + lg * 8];
#pragma unroll
            for (int d = 0; d < 8; ++d) {
                bf16x8 b = *(const bf16x8*)&vts[d * 16 + l15][kk2 * 32 + lg * 8];
                o_acc[d] = __builtin_amdgcn_mfma_f32_16x16x32_bf16(a, b, o_acc[d], 0, 0, 0);
            }
        }
        __builtin_amdgcn_s_setprio(0);
    }

    // epilogue: divide by l, store bf16 o[s][h*128+dv]
#pragma unroll
    for (int d = 0; d < 8; ++d)
#pragma unroll
        for (int r = 0; r < 4; ++r) {
            int srow = s0q + w * 16 + lg * 4 + r;
            float v = o_acc[d][r] / l_r[r];
            o_g[srow * 16384 + h * 128 + d * 16 + l15] = f2bf(v);
        }
}

// ---------------- host launcher ----------------
extern "C" void kernel_launch(void* const* d_in, const int* in_sizes, int n_in,
                              void* d_out, int out_size, void* d_ws, size_t ws_size,
                              hipStream_t stream) {
    const float* hs        = (const float*)d_in[0];
    const float* w_q_down  = (const float*)d_in[1];
    const float* q_norm_w  = (const float*)d_in[2];
    const float* w_q_up    = (const float*)d_in[3];
    const float* w_kv_down = (const float*)d_in[4];
    const float* kv_norm_w = (const float*)d_in[5];
    const float* w_kv_up   = (const float*)d_in[6];
    const float* w_out     = (const float*)d_in[7];
    float* out = (float*)d_out;
    char* ws = (char*)d_ws;

    // ---- workspace layout (contiguous front region is reused for w_out bf16) ----
    const size_t SZ_HS   = (size_t)SEQ * HIDN * 2;            // 14,680,064
    const size_t SZ_KV   = (size_t)SEQ * 32768 * 2;           // 67,108,864
    const size_t SZ_QCR  = (size_t)SEQ * (NHEAD * 192) * 2;   // 50,331,648
    const size_t SZ_VT   = (size_t)NHEAD * 128 * 1024 * 2;    // 33,554,432
    const size_t SZ_WB   = (size_t)24576 * 1536 * 2;          // 75,497,472 (max of small weights)
    const size_t SZ_CQ   = (size_t)SEQ * QLRANK * 4;
    const size_t SZ_CQN  = (size_t)SEQ * QLRANK * 2;
    const size_t SZ_CKV  = (size_t)SEQ * 576 * 4;
    const size_t SZ_CKVN = (size_t)SEQ * KVLRANK * 2;
    const size_t SZ_KR   = (size_t)SEQ * 64 * 2;
    const size_t SZ_OG   = (size_t)SEQ * 16384 * 2;
    const size_t SZ_TAB  = (size_t)SEQ * 32 * 4;

    size_t off = 0;
    u16* hs_bf  = (u16*)(ws + off); off += SZ_HS;
    u16* kvb    = (u16*)(ws + off); off += SZ_KV;
    u16* q_cr   = (u16*)(ws + off); off += SZ_QCR;
    u16* vT     = (u16*)(ws + off); off += SZ_VT;
    u16* W_BUF  = (u16*)(ws + off); off += SZ_WB;
    // split-K partials for c_q/kv_down alias upper W_BUF region (+32MB; weight
    // there is <32MB while these gemms run).
    float* parts = (float*)((char*)W_BUF + 33554432);
    // w_out bf16 (234,881,024 B) aliases [ws .. 235MB), all dead by then
    u16* wout_bf = (u16*)ws;
    float* c_q    = (float*)(ws + off); off += SZ_CQ;
    u16* cq_n     = (u16*)(ws + off); off += SZ_CQN;
    float* ckv_kr = (float*)(ws + off); off += SZ_CKV;
    u16* ckv_n    = (u16*)(ws + off); off += SZ_CKVN;
    u16* kr       = (u16*)(ws + off); off += SZ_KR;
    u16* o_g      = (u16*)(ws + off); off += SZ_OG;
    float* cos_t  = (float*)(ws + off); off += SZ_TAB;
    float* sin_t  = (float*)(ws + off); off += SZ_TAB;
    (void)in_sizes; (void)n_in; (void)out_size; (void)ws_size;

    rope_tables<<<dim3(SEQ), dim3(32), 0, stream>>>(cos_t, sin_t);
    f32_to_bf16<<<2048, 256, 0, stream>>>(hs, hs_bf, (long)SEQ * HIDN);

    // c_q = hs @ w_q_down^T   (split-K x4: 7168 = 4 x 1792)
    f32_to_bf16<<<2048, 256, 0, stream>>>(w_q_down, W_BUF, (long)QLRANK * HIDN);
    gemm_bt<0><<<dim3(QLRANK / 128, SEQ / 128, 4), 512, 0, stream>>>(hs_bf, W_BUF, parts, SEQ, QLRANK, HIDN / 4, HIDN);
    reduce_parts<<<1024, 256, 0, stream>>>(parts, c_q, 4, (long)SEQ * QLRANK);
    rmsnorm_kernel<<<SEQ, 256, 0, stream>>>(c_q, q_norm_w, cq_n, QLRANK, QLRANK);

    // q_cr = rmsnorm(c_q) @ w_q_up^T
    f32_to_bf16<<<2048, 256, 0, stream>>>(w_q_up, W_BUF, (long)24576 * QLRANK);
    gemm_bt<1><<<dim3(24576 / 128, SEQ / 128), 512, 0, stream>>>(cq_n, W_BUF, q_cr, SEQ, 24576, QLRANK, QLRANK);

    // ckv_kr = hs @ w_kv_down^T   (split-K x8; N=576 ragged)
    f32_to_bf16<<<2048, 256, 0, stream>>>(w_kv_down, W_BUF, (long)576 * HIDN);
    gemm_bt<0><<<dim3(5, SEQ / 128, 8), 512, 0, stream>>>(hs_bf, W_BUF, parts, SEQ, 576, HIDN / 8, HIDN);
    reduce_parts<<<1024, 256, 0, stream>>>(parts, ckv_kr, 8, (long)SEQ * 576);
    rmsnorm_kernel<<<SEQ, 256, 0, stream>>>(ckv_kr, kv_norm_w, ckv_n, 576, KVLRANK);
    rope_k<<<SEQ, 64, 0, stream>>>(ckv_kr, cos_t, sin_t, kr);

    // kv = rmsnorm(c_kv) @ w_kv_up^T
    f32_to_bf16<<<2048, 256, 0, stream>>>(w_kv_up, W_BUF, (long)32768 * KVLRANK);
    gemm_bt<1><<<dim3(32768 / 128, SEQ / 128), 512, 0, stream>>>(ckv_n, W_BUF, kvb, SEQ, 32768, KVLRANK, KVLRANK);

    rope_q<<<dim3(SEQ, NHEAD / 2), 64, 0, stream>>>(q_cr, cos_t, sin_t);
    build_vt<<<dim3(NHEAD, SEQ / 64), 256, 0, stream>>>(kvb, vT);

    mla_attn<<<dim3(SEQ / 128, NHEAD), 512, 0, stream>>>(q_cr, kvb, kr, vT, o_g);

    // out = o @ w_out^T   (no split-K; natural order gives same-XCD B-strip reuse)
    f32_to_bf16<<<4096, 256, 0, stream>>>(w_out, wout_bf, (long)HIDN * 16384);
    gemm_bt<0><<<dim3(HIDN / 128, SEQ / 128), 512, 0, stream>>>(o_g, wout_bf, out, SEQ, HIDN, 16384, 16384);
}